// Round 1
// baseline (97.383 us; speedup 1.0000x reference)
//
#include <hip/hip_runtime.h>

#define BATCH 8192
#define HIST  50
#define REPR  512

// One batch row is handled by 128 threads; each thread owns one float4
// (16 B) slice of the 512-dim embedding. A gather of one table row is a
// single coalesced 2048 B access across the 128 threads (2 waves).
// 2 rows per 256-thread block -> grid = BATCH/2 = 4096 blocks.
__global__ __launch_bounds__(256) void embbag_sum_kernel(
    const int* __restrict__ target,      // [BATCH, HIST], -1 = sentinel
    const float* __restrict__ emb,       // [N_EMB, REPR]
    float* __restrict__ out)             // [BATCH, REPR]
{
    const int row  = blockIdx.x * 2 + (threadIdx.x >> 7);  // which batch row
    const int lane = threadIdx.x & 127;                    // float4 slot 0..127

    const int* t = target + row * HIST;
    const float* col = emb + (size_t)lane * 4;

    float4 acc = make_float4(0.f, 0.f, 0.f, 0.f);

#pragma unroll 5
    for (int j = 0; j < HIST; ++j) {
        const int idx = t[j];  // wave-uniform broadcast load
        if (idx >= 0) {
            const float4 v =
                *reinterpret_cast<const float4*>(col + (size_t)idx * REPR);
            acc.x += v.x;
            acc.y += v.y;
            acc.z += v.z;
            acc.w += v.w;
        }
    }

    *reinterpret_cast<float4*>(out + (size_t)row * REPR + (size_t)lane * 4) = acc;
}

extern "C" void kernel_launch(void* const* d_in, const int* in_sizes, int n_in,
                              void* d_out, int out_size, void* d_ws, size_t ws_size,
                              hipStream_t stream) {
    const int*   target = (const int*)d_in[0];
    const float* emb    = (const float*)d_in[1];
    float*       out    = (float*)d_out;

    dim3 grid(BATCH / 2);
    dim3 block(256);
    embbag_sum_kernel<<<grid, block, 0, stream>>>(target, emb, out);
}